// Round 1
// 771.350 us; speedup vs baseline: 1.0091x; 1.0091x over previous
//
#include <hip/hip_runtime.h>
#include <hip/hip_bf16.h>

// Problem constants
#define B_    256
#define N_    2048
#define M_    128
#define VEC_  256
#define H_    1024
#define E_    512
#define P_    134
#define XDIM  384      // VEC + M
#define G4H   4096     // 4*H
#define PWC   524      // P + (P + 2M) = 134 + 390

typedef float  floatx4  __attribute__((ext_vector_type(4)));
typedef short  bf16x8   __attribute__((ext_vector_type(8)));
typedef unsigned short ushortx8 __attribute__((ext_vector_type(8)));
typedef unsigned short ushortx4 __attribute__((ext_vector_type(4)));

// ---- workspace layout: float region ----
#define OFF_GATES 0
#define OFF_H     (OFF_GATES + B_*G4H)
#define OFF_PW    (OFF_H     + B_*H_)
#define OFF_KR    (OFF_PW    + B_*PWC)
#define OFF_KW    (OFF_KR    + B_*M_)
#define OFF_E     (OFF_KW    + B_*M_)
#define OFF_A     (OFF_E     + B_*M_)
#define OFF_SCAL  (OFF_A     + B_*M_)
#define OFF_DOTR  (OFF_SCAL  + B_*16)
#define OFF_DOTW  (OFF_DOTR  + B_*N_)
#define OFF_MNORM (OFF_DOTW  + B_*N_)
#define OFF_WR    (OFF_MNORM + B_*N_)
#define OFF_WW    (OFF_WR    + B_*N_)
#define OFF_READ  (OFF_WW    + B_*N_)
#define FLOAT_TOTAL (OFF_READ + B_*M_)
// ---- bf16 region (shorts), after float region ----
#define SOFF_X    0
#define SOFF_H    (SOFF_X   + B_*XDIM)
#define SOFF_WIH  (SOFF_H   + B_*H_)
#define SOFF_WHH  (SOFF_WIH + G4H*XDIM)
#define SHORT_TOTAL (SOFF_WHH + G4H*H_)

__device__ __forceinline__ float bf2f(unsigned short u) {
    return __uint_as_float(((unsigned int)u) << 16);
}
__device__ __forceinline__ unsigned short f2bf(float f) {
    unsigned int x = __float_as_uint(f);
    x += 0x7fffu + ((x >> 16) & 1u);   // RTNE
    return (unsigned short)(x >> 16);
}
__device__ __forceinline__ float sigm(float x) { return 1.f / (1.f + expf(-x)); }
__device__ __forceinline__ float softplus_(float x) { return x > 20.f ? x : log1pf(expf(x)); }

// ---------------- K0: f32 -> bf16 conversion for the gates GEMM operands ----
__global__ __launch_bounds__(256) void k_cvt4(
    const float* __restrict__ s0, const float* __restrict__ s1,
    const float* __restrict__ s2, const float* __restrict__ s3,
    unsigned short* __restrict__ dst)
{
    int i = (blockIdx.x * 256 + threadIdx.x) * 4;
    const float* s; int off;
    if      (i < SOFF_H)    { s = s0; off = SOFF_X; }
    else if (i < SOFF_WIH)  { s = s1; off = SOFF_H; }
    else if (i < SOFF_WHH)  { s = s2; off = SOFF_WIH; }
    else                    { s = s3; off = SOFF_WHH; }
    floatx4 v = *(const floatx4*)(s + (i - off));
    ushortx4 o;
    o[0] = f2bf(v[0]); o[1] = f2bf(v[1]); o[2] = f2bf(v[2]); o[3] = f2bf(v[3]);
    *(ushortx4*)(dst + i) = o;
}

// ---------------- K1: gates = [x|h_prev] @ [W_ih|W_hh]^T + b (bf16 MFMA) ----
// Retiled: 2048 waves (2/SIMD), each wave owns a 16x32 output tile (2 MFMA cols).
__global__ __launch_bounds__(256) void k_gates(
    const unsigned short* __restrict__ wsb,
    const float* __restrict__ b_ih, const float* __restrict__ b_hh,
    float* __restrict__ gates)                  // [256,4096]
{
    const unsigned short* x      = wsb + SOFF_X;
    const unsigned short* h_prev = wsb + SOFF_H;
    const unsigned short* W_ih   = wsb + SOFF_WIH;
    const unsigned short* W_hh   = wsb + SOFF_WHH;

    int gtid  = blockIdx.x * 256 + threadIdx.x;
    int wid   = gtid >> 6;              // 0..2047
    int lane  = threadIdx.x & 63;
    int tileM = wid >> 7;               // 0..15
    int nGrp  = wid & 127;              // 0..127
    int m0 = tileM << 4, n0 = nGrp << 5;
    int quad = lane >> 4, r16 = lane & 15;
    int koff = quad << 3;
    int mA = m0 + r16;

    floatx4 acc[2];
#pragma unroll
    for (int s = 0; s < 2; ++s) acc[s] = (floatx4){0.f, 0.f, 0.f, 0.f};

    const unsigned short* xrow = x + mA * XDIM;
    const unsigned short* hrow = h_prev + mA * H_;

#pragma unroll 4
    for (int kk = 0; kk < 12; ++kk) {            // K = 0..383 (x / W_ih)
        int k = (kk << 5) + koff;
        bf16x8 a  = *(const bf16x8*)(xrow + k);
        bf16x8 b0 = *(const bf16x8*)(W_ih + (n0 +  0 + r16) * XDIM + k);
        bf16x8 b1 = *(const bf16x8*)(W_ih + (n0 + 16 + r16) * XDIM + k);
        acc[0] = __builtin_amdgcn_mfma_f32_16x16x32_bf16(a, b0, acc[0], 0, 0, 0);
        acc[1] = __builtin_amdgcn_mfma_f32_16x16x32_bf16(a, b1, acc[1], 0, 0, 0);
    }
#pragma unroll 4
    for (int kk = 0; kk < 32; ++kk) {            // K = 384..1407 (h_prev / W_hh)
        int k = (kk << 5) + koff;
        bf16x8 a  = *(const bf16x8*)(hrow + k);
        bf16x8 b0 = *(const bf16x8*)(W_hh + (n0 +  0 + r16) * H_ + k);
        bf16x8 b1 = *(const bf16x8*)(W_hh + (n0 + 16 + r16) * H_ + k);
        acc[0] = __builtin_amdgcn_mfma_f32_16x16x32_bf16(a, b0, acc[0], 0, 0, 0);
        acc[1] = __builtin_amdgcn_mfma_f32_16x16x32_bf16(a, b1, acc[1], 0, 0, 0);
    }
    // C/D layout: col = lane&15, row = quad*4 + reg
#pragma unroll
    for (int s = 0; s < 2; ++s) {
        int n = n0 + (s << 4) + r16;
        float bias = b_ih[n] + b_hh[n];
#pragma unroll
        for (int r = 0; r < 4; ++r) {
            int m = m0 + (quad << 2) + r;
            gates[m * G4H + n] = acc[s][r] + bias;
        }
    }
}

// ---------------- K2: fused LSTM pointwise + head GEMV + head params --------
// One block per batch row. Replaces k_lstm + k_heads + k_params.
__global__ __launch_bounds__(256) void k_ctrl(
    const float* __restrict__ gates, const float* __restrict__ c_prev,
    const float* __restrict__ W_r, const float* __restrict__ b_r,
    const float* __restrict__ W_w, const float* __restrict__ b_w,
    float* __restrict__ h_out,
    float* __restrict__ kr, float* __restrict__ kw,
    float* __restrict__ e,  float* __restrict__ a,
    float* __restrict__ scal, float* __restrict__ read_acc)
{
    __shared__ __align__(16) float hs[H_];
    __shared__ __align__(16) float pws[PWC];
    __shared__ float red[8];
    int b = blockIdx.x, t = threadIdx.x;
    const float* g = gates + (size_t)b * G4H;

    // --- LSTM pointwise: 4 hidden units per thread ---
#pragma unroll
    for (int jj = 0; jj < 4; ++jj) {
        int j = t + (jj << 8);
        float ig = sigm(g[j]);
        float fg = sigm(g[1024 + j]);
        float gg = tanhf(g[2048 + j]);
        float og = sigm(g[3072 + j]);
        float c  = fg * c_prev[b * H_ + j] + ig * gg;
        float hv = og * tanhf(c);
        hs[j] = hv;
        h_out[b * H_ + j] = hv;
    }
    __syncthreads();

    // --- head GEMV: 3 independent accumulator chains per thread ---
    int c0 = t, c1 = t + 256, c2v = (t < 12);
    const float* w0; float bias0;
    if (c0 < P_) { w0 = W_r + c0 * H_; bias0 = b_r[c0]; }
    else         { w0 = W_w + (c0 - P_) * H_; bias0 = b_w[c0 - P_]; }
    const float* w1 = W_w + (c1 - P_) * H_;           // 256..511 all write-head
    float bias1 = b_w[c1 - P_];
    const float* w2 = W_w + (c2v ? (t + 512 - P_) : 0) * H_;
    float acc0 = 0.f, acc1 = 0.f, acc2 = 0.f;
#pragma unroll 4
    for (int k = 0; k < H_; k += 4) {
        floatx4 hv = *(const floatx4*)&hs[k];
        floatx4 a0 = *(const floatx4*)(w0 + k);
        floatx4 a1 = *(const floatx4*)(w1 + k);
        floatx4 a2 = *(const floatx4*)(w2 + k);
#pragma unroll
        for (int j = 0; j < 4; ++j) {
            acc0 = fmaf(a0[j], hv[j], acc0);
            acc1 = fmaf(a1[j], hv[j], acc1);
            acc2 = fmaf(a2[j], hv[j], acc2);
        }
    }
    pws[c0] = acc0 + bias0;
    pws[c1] = acc1 + bias1;
    if (c2v) pws[t + 512] = acc2 + b_w[t + 512 - P_];
    __syncthreads();

    // --- head params (first 128 threads own elementwise work) ---
    float krv = 0.f, kwv = 0.f;
    if (t < 128) {
        krv = tanhf(pws[t]);
        kwv = tanhf(pws[P_ + t]);
        kr[b * M_ + t] = krv;
        kw[b * M_ + t] = kwv;
        e [b * M_ + t] = sigm (pws[268 + t]);
        a [b * M_ + t] = tanhf(pws[396 + t]);
        read_acc[b * M_ + t] = 0.f;
    }
    float sr = krv * krv, sw = kwv * kwv;
#pragma unroll
    for (int m = 32; m; m >>= 1) { sr += __shfl_xor(sr, m); sw += __shfl_xor(sw, m); }
    if ((t & 63) == 0) { red[(t >> 6) * 2] = sr; red[(t >> 6) * 2 + 1] = sw; }
    __syncthreads();
    if (t == 0) {
        float nr = sqrtf(red[0] + red[2] + red[4] + red[6]);
        float nw = sqrtf(red[1] + red[3] + red[5] + red[7]);
        float* sc = scal + b * 16;
        {
            float beta = softplus_(pws[128]);
            float gg   = sigm(pws[129]);
            float s0 = pws[130], s1 = pws[131], s2 = pws[132];
            float mx = fmaxf(s0, fmaxf(s1, s2));
            float e0 = expf(s0 - mx), e1 = expf(s1 - mx), e2 = expf(s2 - mx);
            float es = e0 + e1 + e2;
            sc[0] = beta; sc[1] = gg; sc[2] = e0 / es; sc[3] = e1 / es; sc[4] = e2 / es;
            sc[5] = 1.f + softplus_(pws[133]); sc[6] = nr;
        }
        {
            float beta = softplus_(pws[262]);
            float gg   = sigm(pws[263]);
            float s0 = pws[264], s1 = pws[265], s2 = pws[266];
            float mx = fmaxf(s0, fmaxf(s1, s2));
            float e0 = expf(s0 - mx), e1 = expf(s1 - mx), e2 = expf(s2 - mx);
            float es = e0 + e1 + e2;
            sc[8] = beta; sc[9] = gg; sc[10] = e0 / es; sc[11] = e1 / es; sc[12] = e2 / es;
            sc[13] = 1.f + softplus_(pws[267]); sc[14] = nw;
        }
    }
}

// ---------------- K3: pass 1 over memory: dots + row norms (f32) ----------------
// float4 NT loads (2 rows per wave-load), 5-level butterfly within 32 lanes.
__global__ __launch_bounds__(256) void k_pass1(
    const float* __restrict__ memory,           // [256,2048,128] f32
    const float* __restrict__ kr, const float* __restrict__ kw,
    float* __restrict__ dotr, float* __restrict__ dotw, float* __restrict__ mnorm)
{
    int b = blockIdx.x >> 4;
    int chunk = blockIdx.x & 15;                // 128 rows per block
    __shared__ __align__(16) float krs[M_], kws[M_];
    int t = threadIdx.x;
    if (t < 128) krs[t] = kr[b * M_ + t];
    else         kws[t - 128] = kw[b * M_ + t - 128];
    __syncthreads();
    int wave = t >> 6, lane = t & 63;
    int col  = (lane & 31) << 2;                // 0..124
    int half = lane >> 5;                       // row within pair
    floatx4 kr4 = *(const floatx4*)&krs[col];
    floatx4 kw4 = *(const floatx4*)&kws[col];
    int rowbase = chunk * 128 + wave * 32;
#pragma unroll 4
    for (int i = 0; i < 16; ++i) {
        int n = rowbase + (i << 1) + half;
        size_t ro = (size_t)b * N_ + n;
        floatx4 mv = __builtin_nontemporal_load((const floatx4*)(memory + ro * M_ + col));
        float dr = mv[0] * kr4[0] + mv[1] * kr4[1] + mv[2] * kr4[2] + mv[3] * kr4[3];
        float dw = mv[0] * kw4[0] + mv[1] * kw4[1] + mv[2] * kw4[2] + mv[3] * kw4[3];
        float ss = mv[0] * mv[0] + mv[1] * mv[1] + mv[2] * mv[2] + mv[3] * mv[3];
#pragma unroll
        for (int m = 16; m; m >>= 1) {
            dr += __shfl_xor(dr, m);
            dw += __shfl_xor(dw, m);
            ss += __shfl_xor(ss, m);
        }
        if ((lane & 31) == 0) {
            dotr[ro] = dr; dotw[ro] = dw; mnorm[ro] = sqrtf(ss);
        }
    }
}

// ---------------- K4: addressing ----------------
__device__ __forceinline__ float blkSum(float v, float* red) {
#pragma unroll
    for (int m = 32; m; m >>= 1) v += __shfl_xor(v, m);
    int w = threadIdx.x >> 6;
    if ((threadIdx.x & 63) == 0) red[w] = v;
    __syncthreads();
    float r = red[0] + red[1] + red[2] + red[3];
    __syncthreads();
    return r;
}
__device__ __forceinline__ float blkMax(float v, float* red) {
#pragma unroll
    for (int m = 32; m; m >>= 1) v = fmaxf(v, __shfl_xor(v, m));
    int w = threadIdx.x >> 6;
    if ((threadIdx.x & 63) == 0) red[w] = v;
    __syncthreads();
    float r = fmaxf(fmaxf(red[0], red[1]), fmaxf(red[2], red[3]));
    __syncthreads();
    return r;
}

__global__ __launch_bounds__(256) void k_address(
    const float* __restrict__ dotr, const float* __restrict__ dotw,
    const float* __restrict__ mnorm,
    const float* __restrict__ prev_r, const float* __restrict__ prev_w,
    const float* __restrict__ scal,
    float* __restrict__ wr, float* __restrict__ ww)
{
    int b = blockIdx.x >> 1, head = blockIdx.x & 1;
    const float* dot = head ? dotw : dotr;
    const float* prev = head ? prev_w : prev_r;
    float* wout = head ? ww : wr;
    const float* sc = scal + b * 16 + head * 8;
    float beta = sc[0], g = sc[1], s0 = sc[2], s1 = sc[3], s2 = sc[4];
    float gamma = sc[5], kn = sc[6];

    __shared__ float buf[N_];
    __shared__ float red[4];
    int t = threadIdx.x;
    size_t base = (size_t)b * N_;

    float loc[8];
    float mx = -1e30f;
#pragma unroll
    for (int i = 0; i < 8; ++i) {
        int n = (i << 8) + t;
        float xv = beta * dot[base + n] / (mnorm[base + n] * kn + 1e-16f);
        loc[i] = xv;
        mx = fmaxf(mx, xv);
    }
    mx = blkMax(mx, red);
    float sum = 0.f;
#pragma unroll
    for (int i = 0; i < 8; ++i) { float ev = expf(loc[i] - mx); loc[i] = ev; sum += ev; }
    sum = blkSum(sum, red);
    float inv = 1.f / sum;
#pragma unroll
    for (int i = 0; i < 8; ++i) {
        int n = (i << 8) + t;
        float wc = loc[i] * inv;
        buf[n] = g * wc + (1.f - g) * prev[base + n];
    }
    __syncthreads();
    float psum = 0.f;
#pragma unroll
    for (int i = 0; i < 8; ++i) {
        int n = (i << 8) + t;
        float wt = s0 * buf[(n + N_ - 1) & (N_ - 1)] + s1 * buf[n] + s2 * buf[(n + 1) & (N_ - 1)];
        float wp = powf(wt, gamma);
        loc[i] = wp;
        psum += wp;
    }
    psum = blkSum(psum, red);
    float invp = 1.f / (psum + 1e-16f);
#pragma unroll
    for (int i = 0; i < 8; ++i) {
        int n = (i << 8) + t;
        wout[base + n] = loc[i] * invp;
    }
}

// ---------------- K5: memory update + read reduction (all f32) -----
// 64 rows per block (half the blocks/atomics of before), NT streaming.
__global__ __launch_bounds__(256) void k_update(
    const float* __restrict__ memory,
    const float* __restrict__ wr, const float* __restrict__ ww,
    const float* __restrict__ e, const float* __restrict__ a,
    float* __restrict__ read_acc,
    float* __restrict__ newmem)
{
    int b = blockIdx.x >> 5;
    int chunk = blockIdx.x & 31;                // 64 rows per block
    int t = threadIdx.x;
    __shared__ float es[M_], as_[M_];
    if (t < 128) es[t] = e[b * M_ + t];
    else         as_[t - 128] = a[b * M_ + t - 128];
    __syncthreads();

    int c = t & 15, r = t >> 4;
    int m8 = c << 3;
    float ev[8], av[8], racc[8];
#pragma unroll
    for (int j = 0; j < 8; ++j) { ev[j] = es[m8 + j]; av[j] = as_[m8 + j]; racc[j] = 0.f; }

#pragma unroll
    for (int stp = 0; stp < 4; ++stp) {
        int n = chunk * 64 + stp * 16 + r;
        size_t ro = (size_t)b * N_ + n;
        floatx4 mv0 = __builtin_nontemporal_load((const floatx4*)(memory + ro * M_ + m8));
        floatx4 mv1 = __builtin_nontemporal_load((const floatx4*)(memory + ro * M_ + m8 + 4));
        float wwv = ww[ro], wrv = wr[ro];
        floatx4 o0, o1;
#pragma unroll
        for (int j = 0; j < 4; ++j) {
            float mf = mv0[j];
            o0[j] = mf * (1.f - wwv * ev[j]) + wwv * av[j];
            racc[j] = fmaf(wrv, mf, racc[j]);
        }
#pragma unroll
        for (int j = 0; j < 4; ++j) {
            float mf = mv1[j];
            o1[j] = mf * (1.f - wwv * ev[4 + j]) + wwv * av[4 + j];
            racc[4 + j] = fmaf(wrv, mf, racc[4 + j]);
        }
        __builtin_nontemporal_store(o0, (floatx4*)(newmem + ro * M_ + m8));
        __builtin_nontemporal_store(o1, (floatx4*)(newmem + ro * M_ + m8 + 4));
    }

    __shared__ float rbuf[16][M_];
#pragma unroll
    for (int j = 0; j < 8; ++j) rbuf[r][m8 + j] = racc[j];
    __syncthreads();
    if (t < 128) {
        float s = 0.f;
#pragma unroll
        for (int rr = 0; rr < 16; ++rr) s += rbuf[rr][t];
        atomicAdd(read_acc + b * M_ + t, s);
    }
}

// ---------------- K6: output FC + sigmoid (f32 out) ----------------
__global__ __launch_bounds__(256) void k_out(
    const float* __restrict__ h, const float* __restrict__ read_acc,
    const float* __restrict__ W_fc, const float* __restrict__ b_fc,
    float* __restrict__ out)
{
    __shared__ __align__(16) float hc[H_ + M_];
    int b = blockIdx.x, t = threadIdx.x;
    for (int i = t; i < H_; i += 256) hc[i] = h[b * H_ + i];
    if (t < 128) hc[H_ + t] = read_acc[b * M_ + t];
    __syncthreads();
    int c0 = t, c1 = t + 256;
    const float* w0 = W_fc + c0 * (H_ + M_);
    const float* w1 = W_fc + c1 * (H_ + M_);
    float acc0 = 0.f, acc1 = 0.f;
#pragma unroll 4
    for (int k = 0; k < H_ + M_; k += 4) {
        floatx4 hv = *(const floatx4*)&hc[k];
        floatx4 a0 = *(const floatx4*)(w0 + k);
        floatx4 a1 = *(const floatx4*)(w1 + k);
#pragma unroll
        for (int j = 0; j < 4; ++j) {
            acc0 = fmaf(a0[j], hv[j], acc0);
            acc1 = fmaf(a1[j], hv[j], acc1);
        }
    }
    out[b * E_ + c0] = sigm(acc0 + b_fc[c0]);
    out[b * E_ + c1] = sigm(acc1 + b_fc[c1]);
}

extern "C" void kernel_launch(void* const* d_in, const int* in_sizes, int n_in,
                              void* d_out, int out_size, void* d_ws, size_t ws_size,
                              hipStream_t stream)
{
    (void)in_sizes; (void)n_in; (void)out_size; (void)ws_size;
    const float* x      = (const float*)d_in[0];
    const float* memory = (const float*)d_in[1];
    const float* prev_r = (const float*)d_in[2];
    const float* prev_w = (const float*)d_in[3];
    const float* h_prev = (const float*)d_in[4];
    const float* c_prev = (const float*)d_in[5];
    const float* W_ih   = (const float*)d_in[6];
    const float* W_hh   = (const float*)d_in[7];
    const float* b_ih   = (const float*)d_in[8];
    const float* b_hh   = (const float*)d_in[9];
    const float* W_r    = (const float*)d_in[10];
    const float* b_r    = (const float*)d_in[11];
    const float* W_w    = (const float*)d_in[12];
    const float* b_w    = (const float*)d_in[13];
    const float* W_fc   = (const float*)d_in[14];
    const float* b_fc   = (const float*)d_in[15];

    float* ws = (float*)d_ws;
    float* gates = ws + OFF_GATES;
    float* h     = ws + OFF_H;
    float* kr    = ws + OFF_KR;
    float* kw    = ws + OFF_KW;
    float* e     = ws + OFF_E;
    float* a     = ws + OFF_A;
    float* scal  = ws + OFF_SCAL;
    float* dotr  = ws + OFF_DOTR;
    float* dotw  = ws + OFF_DOTW;
    float* mnorm = ws + OFF_MNORM;
    float* wrb   = ws + OFF_WR;
    float* wwb   = ws + OFF_WW;
    float* rd    = ws + OFF_READ;
    unsigned short* wsb = (unsigned short*)(ws + FLOAT_TOTAL);

    float* out    = (float*)d_out;
    float* newmem = out + B_ * E_;              // new_memory after out (f32)

    k_cvt4   <<<SHORT_TOTAL / 1024, 256, 0, stream>>>(x, h_prev, W_ih, W_hh, wsb);
    k_gates  <<<512,   256, 0, stream>>>(wsb, b_ih, b_hh, gates);
    k_ctrl   <<<256,   256, 0, stream>>>(gates, c_prev, W_r, b_r, W_w, b_w,
                                         h, kr, kw, e, a, scal, rd);
    k_pass1  <<<4096,  256, 0, stream>>>(memory, kr, kw, dotr, dotw, mnorm);
    k_address<<<512,   256, 0, stream>>>(dotr, dotw, mnorm, prev_r, prev_w, scal, wrb, wwb);
    k_update <<<8192,  256, 0, stream>>>(memory, wrb, wwb, e, a, rd, newmem);
    k_out    <<<256,   256, 0, stream>>>(h, rd, W_fc, b_fc, out);
}

// Round 2
// 721.719 us; speedup vs baseline: 1.0785x; 1.0688x over previous
//
#include <hip/hip_runtime.h>
#include <hip/hip_bf16.h>

// Problem constants
#define B_    256
#define N_    2048
#define M_    128
#define VEC_  256
#define H_    1024
#define E_    512
#define P_    134
#define XDIM  384      // VEC + M
#define G4H   4096     // 4*H
#define PWC   524      // P + (P + 2M) = 134 + 390

typedef float  floatx4  __attribute__((ext_vector_type(4)));
typedef short  bf16x8   __attribute__((ext_vector_type(8)));
typedef unsigned short ushortx8 __attribute__((ext_vector_type(8)));
typedef unsigned short ushortx4 __attribute__((ext_vector_type(4)));

// ---- workspace layout: float region ----
#define OFF_GATES 0
#define OFF_H     (OFF_GATES + B_*G4H)
#define OFF_KR    (OFF_H     + B_*H_)
#define OFF_KW    (OFF_KR    + B_*M_)
#define OFF_E     (OFF_KW    + B_*M_)
#define OFF_A     (OFF_E     + B_*M_)
#define OFF_SCAL  (OFF_A     + B_*M_)
#define OFF_DOTR  (OFF_SCAL  + B_*16)
#define OFF_DOTW  (OFF_DOTR  + B_*N_)
#define OFF_MNORM (OFF_DOTW  + B_*N_)
#define OFF_WR    (OFF_MNORM + B_*N_)
#define OFF_WW    (OFF_WR    + B_*N_)
#define OFF_RDP   (OFF_WW    + B_*N_)          // read partials [B][16][128]
#define FLOAT_TOTAL (OFF_RDP + B_*16*M_)
// ---- bf16 region (shorts), after float region: x and h only ----
#define SOFF_X    0
#define SOFF_H    (SOFF_X   + B_*XDIM)         // 98,304
#define SHORT_TOTAL (SOFF_H + B_*H_)           // 360,448 shorts

__device__ __forceinline__ unsigned short f2bf(float f) {
    unsigned int x = __float_as_uint(f);
    x += 0x7fffu + ((x >> 16) & 1u);   // RTNE
    return (unsigned short)(x >> 16);
}
__device__ __forceinline__ float sigm(float x) { return 1.f / (1.f + expf(-x)); }
__device__ __forceinline__ float softplus_(float x) { return x > 20.f ? x : log1pf(expf(x)); }

// DPP rotate-add within 16-lane rows (VALU pipe, not DS)
#define DPP_ADD(v, ctrl) \
    v += __int_as_float(__builtin_amdgcn_update_dpp(0, __float_as_int(v), ctrl, 0xF, 0xF, true))

// ---------------- K0: f32 -> bf16 conversion for x / h_prev only ----
__global__ __launch_bounds__(256) void k_cvt2(
    const float* __restrict__ x, const float* __restrict__ h,
    unsigned short* __restrict__ dst)
{
    int i = (blockIdx.x * 256 + threadIdx.x) * 4;
    const float* s; int off;
    if (i < SOFF_H) { s = x; off = SOFF_X; }
    else            { s = h; off = SOFF_H; }
    floatx4 v = *(const floatx4*)(s + (i - off));
    ushortx4 o;
    o[0] = f2bf(v[0]); o[1] = f2bf(v[1]); o[2] = f2bf(v[2]); o[3] = f2bf(v[3]);
    *(ushortx4*)(dst + i) = o;
}

// ---------------- K1: gates = [x|h_prev] @ [W_ih|W_hh]^T + b (bf16 MFMA) ----
// Block = 16 output columns. B-panel (16 x 1408 bf16, 45 KB) staged in LDS
// ONCE per block (f32->bf16 RTNE in-register, bit-identical to old path),
// XOR-swizzled vs the 2816-B row stride. Each wave holds 4 M-tiles so each
// B-fragment ds_read feeds 4 MFMAs. B read once from HBM; A panel (721 KB
// bf16) is L2-resident across blocks.
__global__ __launch_bounds__(256) void k_gates(
    const unsigned short* __restrict__ wsb,
    const float* __restrict__ W_ih, const float* __restrict__ W_hh,
    const float* __restrict__ b_ih, const float* __restrict__ b_hh,
    float* __restrict__ gates)                  // [256,4096]
{
    __shared__ unsigned short Bp[16 * 1408];    // 45,056 B
    char* Bb = (char*)Bp;
    const unsigned short* xb = wsb + SOFF_X;
    const unsigned short* hb = wsb + SOFF_H;

    int n0 = blockIdx.x << 4;                   // 0..4080
    int t  = threadIdx.x;

    // ---- stage B panel: 16 rows x 1408 shorts = 2816 chunks of 8 ----
#pragma unroll
    for (int it = 0; it < 11; ++it) {
        int j   = it * 256 + t;                 // 0..2815
        int row = j / 176;
        int co8 = (j - row * 176) * 8;          // short offset in row
        const float* src = (co8 < 384)
            ? (W_ih + (size_t)(n0 + row) * XDIM + co8)
            : (W_hh + (size_t)(n0 + row) * H_ + (co8 - 384));
        floatx4 f0 = *(const floatx4*)src;
        floatx4 f1 = *(const floatx4*)(src + 4);
        ushortx8 o;
        o[0] = f2bf(f0[0]); o[1] = f2bf(f0[1]); o[2] = f2bf(f0[2]); o[3] = f2bf(f0[3]);
        o[4] = f2bf(f1[0]); o[5] = f2bf(f1[1]); o[6] = f2bf(f1[2]); o[7] = f2bf(f1[3]);
        int kb  = co8 * 2;                      // byte offset in row
        int dst = row * 2816 + (kb ^ ((row & 7) << 4));
        *(ushortx8*)(Bb + dst) = o;
    }
    __syncthreads();

    int w    = t >> 6;                          // wave 0..3 -> m-tiles 4w..4w+3
    int lane = t & 63;
    int quad = lane >> 4, r16 = lane & 15;
    int swz  = (r16 & 7) << 4;
    const char* Brow = Bb + r16 * 2816;

    const unsigned short* xr[4];
    const unsigned short* hr[4];
#pragma unroll
    for (int mi = 0; mi < 4; ++mi) {
        int mA = ((w << 2) + mi) * 16 + r16;
        xr[mi] = xb + mA * XDIM;
        hr[mi] = hb + mA * H_;
    }
    floatx4 acc[4];
#pragma unroll
    for (int mi = 0; mi < 4; ++mi) acc[mi] = (floatx4){0.f, 0.f, 0.f, 0.f};

#pragma unroll 4
    for (int kk = 0; kk < 12; ++kk) {           // K = 0..383 (x region)
        int k0 = (kk << 5) + (quad << 3);       // shorts
        bf16x8 b = *(const bf16x8*)(Brow + (((kk << 6) + (quad << 4)) ^ swz));
#pragma unroll
        for (int mi = 0; mi < 4; ++mi) {
            bf16x8 a = *(const bf16x8*)(xr[mi] + k0);
            acc[mi] = __builtin_amdgcn_mfma_f32_16x16x32_bf16(a, b, acc[mi], 0, 0, 0);
        }
    }
#pragma unroll 4
    for (int kk = 0; kk < 32; ++kk) {           // K = 384..1407 (h region)
        int k0 = (kk << 5) + (quad << 3);       // shorts into h row
        bf16x8 b = *(const bf16x8*)(Brow + ((768 + (kk << 6) + (quad << 4)) ^ swz));
#pragma unroll
        for (int mi = 0; mi < 4; ++mi) {
            bf16x8 a = *(const bf16x8*)(hr[mi] + k0);
            acc[mi] = __builtin_amdgcn_mfma_f32_16x16x32_bf16(a, b, acc[mi], 0, 0, 0);
        }
    }
    // C/D layout: col = lane&15 -> n, row = quad*4 + r -> m
    int n = n0 + r16;
    float bias = b_ih[n] + b_hh[n];
#pragma unroll
    for (int mi = 0; mi < 4; ++mi) {
        int mbase = ((w << 2) + mi) * 16 + (quad << 2);
#pragma unroll
        for (int r = 0; r < 4; ++r)
            gates[(mbase + r) * G4H + n] = acc[mi][r] + bias;
    }
}

// ---------------- K2: fused LSTM pointwise + head GEMV + head params --------
__global__ __launch_bounds__(256) void k_ctrl(
    const float* __restrict__ gates, const float* __restrict__ c_prev,
    const float* __restrict__ W_r, const float* __restrict__ b_r,
    const float* __restrict__ W_w, const float* __restrict__ b_w,
    float* __restrict__ h_out,
    float* __restrict__ kr, float* __restrict__ kw,
    float* __restrict__ e,  float* __restrict__ a,
    float* __restrict__ scal)
{
    __shared__ __align__(16) float hs[H_];
    __shared__ __align__(16) float pws[PWC];
    __shared__ float red[8];
    int b = blockIdx.x, t = threadIdx.x;
    const float* g = gates + (size_t)b * G4H;

#pragma unroll
    for (int jj = 0; jj < 4; ++jj) {
        int j = t + (jj << 8);
        float ig = sigm(g[j]);
        float fg = sigm(g[1024 + j]);
        float gg = tanhf(g[2048 + j]);
        float og = sigm(g[3072 + j]);
        float c  = fg * c_prev[b * H_ + j] + ig * gg;
        float hv = og * tanhf(c);
        hs[j] = hv;
        h_out[b * H_ + j] = hv;
    }
    __syncthreads();

    int c0 = t, c1 = t + 256, c2v = (t < 12);
    const float* w0; float bias0;
    if (c0 < P_) { w0 = W_r + c0 * H_; bias0 = b_r[c0]; }
    else         { w0 = W_w + (c0 - P_) * H_; bias0 = b_w[c0 - P_]; }
    const float* w1 = W_w + (c1 - P_) * H_;
    float bias1 = b_w[c1 - P_];
    const float* w2 = W_w + (c2v ? (t + 512 - P_) : 0) * H_;
    float acc0 = 0.f, acc1 = 0.f, acc2 = 0.f;
#pragma unroll 4
    for (int k = 0; k < H_; k += 4) {
        floatx4 hv = *(const floatx4*)&hs[k];
        floatx4 a0 = *(const floatx4*)(w0 + k);
        floatx4 a1 = *(const floatx4*)(w1 + k);
        floatx4 a2 = *(const floatx4*)(w2 + k);
#pragma unroll
        for (int j = 0; j < 4; ++j) {
            acc0 = fmaf(a0[j], hv[j], acc0);
            acc1 = fmaf(a1[j], hv[j], acc1);
            acc2 = fmaf(a2[j], hv[j], acc2);
        }
    }
    pws[c0] = acc0 + bias0;
    pws[c1] = acc1 + bias1;
    if (c2v) pws[t + 512] = acc2 + b_w[t + 512 - P_];
    __syncthreads();

    float krv = 0.f, kwv = 0.f;
    if (t < 128) {
        krv = tanhf(pws[t]);
        kwv = tanhf(pws[P_ + t]);
        kr[b * M_ + t] = krv;
        kw[b * M_ + t] = kwv;
        e [b * M_ + t] = sigm (pws[268 + t]);
        a [b * M_ + t] = tanhf(pws[396 + t]);
    }
    float sr = krv * krv, sw = kwv * kwv;
#pragma unroll
    for (int m = 32; m; m >>= 1) { sr += __shfl_xor(sr, m); sw += __shfl_xor(sw, m); }
    if ((t & 63) == 0) { red[(t >> 6) * 2] = sr; red[(t >> 6) * 2 + 1] = sw; }
    __syncthreads();
    if (t == 0) {
        float nr = sqrtf(red[0] + red[2] + red[4] + red[6]);
        float nw = sqrtf(red[1] + red[3] + red[5] + red[7]);
        float* sc = scal + b * 16;
        {
            float beta = softplus_(pws[128]);
            float gg   = sigm(pws[129]);
            float s0 = pws[130], s1 = pws[131], s2 = pws[132];
            float mx = fmaxf(s0, fmaxf(s1, s2));
            float e0 = expf(s0 - mx), e1 = expf(s1 - mx), e2 = expf(s2 - mx);
            float es = e0 + e1 + e2;
            sc[0] = beta; sc[1] = gg; sc[2] = e0 / es; sc[3] = e1 / es; sc[4] = e2 / es;
            sc[5] = 1.f + softplus_(pws[133]); sc[6] = nr;
        }
        {
            float beta = softplus_(pws[262]);
            float gg   = sigm(pws[263]);
            float s0 = pws[264], s1 = pws[265], s2 = pws[266];
            float mx = fmaxf(s0, fmaxf(s1, s2));
            float e0 = expf(s0 - mx), e1 = expf(s1 - mx), e2 = expf(s2 - mx);
            float es = e0 + e1 + e2;
            sc[8] = beta; sc[9] = gg; sc[10] = e0 / es; sc[11] = e1 / es; sc[12] = e2 / es;
            sc[13] = 1.f + softplus_(pws[267]); sc[14] = nw;
        }
    }
}

// ---------------- K3: pass 1 over memory: dots + row norms (f32) ----------------
// Normal (L3-allocating) loads so k_update's re-read can hit Infinity Cache.
// Reduction: 4 DPP row_ror adds (VALU pipe) + 1 shfl_xor(16) instead of 5 shfl.
__global__ __launch_bounds__(256) void k_pass1(
    const float* __restrict__ memory,           // [256,2048,128] f32
    const float* __restrict__ kr, const float* __restrict__ kw,
    float* __restrict__ dotr, float* __restrict__ dotw, float* __restrict__ mnorm)
{
    int b = blockIdx.x >> 4;
    int chunk = blockIdx.x & 15;                // 128 rows per block
    __shared__ __align__(16) float krs[M_], kws[M_];
    int t = threadIdx.x;
    if (t < 128) krs[t] = kr[b * M_ + t];
    else         kws[t - 128] = kw[b * M_ + t - 128];
    __syncthreads();
    int wave = t >> 6, lane = t & 63;
    int col  = (lane & 31) << 2;                // 0..124
    int half = lane >> 5;                       // row within pair
    floatx4 kr4 = *(const floatx4*)&krs[col];
    floatx4 kw4 = *(const floatx4*)&kws[col];
    int rowbase = chunk * 128 + wave * 32;
#pragma unroll 4
    for (int i = 0; i < 16; ++i) {
        int n = rowbase + (i << 1) + half;
        size_t ro = (size_t)b * N_ + n;
        floatx4 mv = *(const floatx4*)(memory + ro * M_ + col);
        float dr = mv[0] * kr4[0] + mv[1] * kr4[1] + mv[2] * kr4[2] + mv[3] * kr4[3];
        float dw = mv[0] * kw4[0] + mv[1] * kw4[1] + mv[2] * kw4[2] + mv[3] * kw4[3];
        float ss = mv[0] * mv[0] + mv[1] * mv[1] + mv[2] * mv[2] + mv[3] * mv[3];
        DPP_ADD(dr, 0x128); DPP_ADD(dw, 0x128); DPP_ADD(ss, 0x128);
        DPP_ADD(dr, 0x124); DPP_ADD(dw, 0x124); DPP_ADD(ss, 0x124);
        DPP_ADD(dr, 0x122); DPP_ADD(dw, 0x122); DPP_ADD(ss, 0x122);
        DPP_ADD(dr, 0x121); DPP_ADD(dw, 0x121); DPP_ADD(ss, 0x121);
        dr += __shfl_xor(dr, 16);
        dw += __shfl_xor(dw, 16);
        ss += __shfl_xor(ss, 16);
        if ((lane & 31) == 0) {
            dotr[ro] = dr; dotw[ro] = dw; mnorm[ro] = sqrtf(ss);
        }
    }
}

// ---------------- K4: addressing ----------------
__device__ __forceinline__ float blkSum(float v, float* red) {
#pragma unroll
    for (int m = 32; m; m >>= 1) v += __shfl_xor(v, m);
    int w = threadIdx.x >> 6;
    if ((threadIdx.x & 63) == 0) red[w] = v;
    __syncthreads();
    float r = red[0] + red[1] + red[2] + red[3];
    __syncthreads();
    return r;
}
__device__ __forceinline__ float blkMax(float v, float* red) {
#pragma unroll
    for (int m = 32; m; m >>= 1) v = fmaxf(v, __shfl_xor(v, m));
    int w = threadIdx.x >> 6;
    if ((threadIdx.x & 63) == 0) red[w] = v;
    __syncthreads();
    float r = fmaxf(fmaxf(red[0], red[1]), fmaxf(red[2], red[3]));
    __syncthreads();
    return r;
}

__global__ __launch_bounds__(256) void k_address(
    const float* __restrict__ dotr, const float* __restrict__ dotw,
    const float* __restrict__ mnorm,
    const float* __restrict__ prev_r, const float* __restrict__ prev_w,
    const float* __restrict__ scal,
    float* __restrict__ wr, float* __restrict__ ww)
{
    int b = blockIdx.x >> 1, head = blockIdx.x & 1;
    const float* dot = head ? dotw : dotr;
    const float* prev = head ? prev_w : prev_r;
    float* wout = head ? ww : wr;
    const float* sc = scal + b * 16 + head * 8;
    float beta = sc[0], g = sc[1], s0 = sc[2], s1 = sc[3], s2 = sc[4];
    float gamma = sc[5], kn = sc[6];

    __shared__ float buf[N_];
    __shared__ float red[4];
    int t = threadIdx.x;
    size_t base = (size_t)b * N_;

    float loc[8];
    float mx = -1e30f;
#pragma unroll
    for (int i = 0; i < 8; ++i) {
        int n = (i << 8) + t;
        float xv = beta * dot[base + n] / (mnorm[base + n] * kn + 1e-16f);
        loc[i] = xv;
        mx = fmaxf(mx, xv);
    }
    mx = blkMax(mx, red);
    float sum = 0.f;
#pragma unroll
    for (int i = 0; i < 8; ++i) { float ev = __expf(loc[i] - mx); loc[i] = ev; sum += ev; }
    sum = blkSum(sum, red);
    float inv = 1.f / sum;
#pragma unroll
    for (int i = 0; i < 8; ++i) {
        int n = (i << 8) + t;
        float wc = loc[i] * inv;
        buf[n] = g * wc + (1.f - g) * prev[base + n];
    }
    __syncthreads();
    float psum = 0.f;
#pragma unroll
    for (int i = 0; i < 8; ++i) {
        int n = (i << 8) + t;
        float wt = s0 * buf[(n + N_ - 1) & (N_ - 1)] + s1 * buf[n] + s2 * buf[(n + 1) & (N_ - 1)];
        float wp = __powf(wt, gamma);
        loc[i] = wp;
        psum += wp;
    }
    psum = blkSum(psum, red);
    float invp = 1.f / (psum + 1e-16f);
#pragma unroll
    for (int i = 0; i < 8; ++i) {
        int n = (i << 8) + t;
        wout[base + n] = loc[i] * invp;
    }
}

// ---------------- K5: memory update + read partials (no atomics) -----
// 128 rows/block; block order REVERSED so early blocks re-read the rows
// most recently L3-resident from k_pass1. NT stores avoid RFO/L3 pollution.
__global__ __launch_bounds__(256) void k_update(
    const float* __restrict__ memory,
    const float* __restrict__ wr, const float* __restrict__ ww,
    const float* __restrict__ e, const float* __restrict__ a,
    float* __restrict__ rd_part,
    float* __restrict__ newmem)
{
    int j = 4095 - (int)blockIdx.x;
    int b = j >> 4;
    int chunk = j & 15;                         // 128 rows per block
    int t = threadIdx.x;
    __shared__ float es[M_], as_[M_];
    if (t < 128) es[t] = e[b * M_ + t];
    else         as_[t - 128] = a[b * M_ + t - 128];
    __syncthreads();

    int c = t & 15, r = t >> 4;
    int m8 = c << 3;
    float ev[8], av[8], racc[8];
#pragma unroll
    for (int jj = 0; jj < 8; ++jj) { ev[jj] = es[m8 + jj]; av[jj] = as_[m8 + jj]; racc[jj] = 0.f; }

#pragma unroll
    for (int stp = 0; stp < 8; ++stp) {
        int n = chunk * 128 + stp * 16 + r;
        size_t ro = (size_t)b * N_ + n;
        floatx4 mv0 = *(const floatx4*)(memory + ro * M_ + m8);
        floatx4 mv1 = *(const floatx4*)(memory + ro * M_ + m8 + 4);
        float wwv = ww[ro], wrv = wr[ro];
        floatx4 o0, o1;
#pragma unroll
        for (int jj = 0; jj < 4; ++jj) {
            float mf = mv0[jj];
            o0[jj] = mf * (1.f - wwv * ev[jj]) + wwv * av[jj];
            racc[jj] = fmaf(wrv, mf, racc[jj]);
        }
#pragma unroll
        for (int jj = 0; jj < 4; ++jj) {
            float mf = mv1[jj];
            o1[jj] = mf * (1.f - wwv * ev[4 + jj]) + wwv * av[4 + jj];
            racc[4 + jj] = fmaf(wrv, mf, racc[4 + jj]);
        }
        __builtin_nontemporal_store(o0, (floatx4*)(newmem + ro * M_ + m8));
        __builtin_nontemporal_store(o1, (floatx4*)(newmem + ro * M_ + m8 + 4));
    }

    __shared__ float rbuf[16][M_];
#pragma unroll
    for (int jj = 0; jj < 8; ++jj) rbuf[r][m8 + jj] = racc[jj];
    __syncthreads();
    if (t < 128) {
        float s = 0.f;
#pragma unroll
        for (int rr = 0; rr < 16; ++rr) s += rbuf[rr][t];
        rd_part[((b << 4) + chunk) * M_ + t] = s;
    }
}

// ---------------- K6: output FC + sigmoid (f32), 2 blocks/batch ----------------
__global__ __launch_bounds__(256) void k_out(
    const float* __restrict__ h, const float* __restrict__ rd_part,
    const float* __restrict__ W_fc, const float* __restrict__ b_fc,
    float* __restrict__ out)
{
    __shared__ __align__(16) float hc[H_ + M_];
    int b = blockIdx.x >> 1, half = blockIdx.x & 1;
    int t = threadIdx.x;
    for (int i = t; i < H_; i += 256) hc[i] = h[b * H_ + i];
    if (t < 128) {
        float s = 0.f;
#pragma unroll
        for (int p = 0; p < 16; ++p) s += rd_part[((b << 4) + p) * M_ + t];
        hc[H_ + t] = s;
    }
    __syncthreads();
    int c = half * 256 + t;
    const float* wrow = W_fc + c * (H_ + M_);
    float acc0 = 0.f, acc1 = 0.f;
#pragma unroll 4
    for (int k = 0; k < H_ + M_; k += 8) {
        floatx4 w0 = *(const floatx4*)(wrow + k);
        floatx4 w1 = *(const floatx4*)(wrow + k + 4);
        floatx4 h0 = *(const floatx4*)&hc[k];
        floatx4 h1 = *(const floatx4*)&hc[k + 4];
#pragma unroll
        for (int jj = 0; jj < 4; ++jj) {
            acc0 = fmaf(w0[jj], h0[jj], acc0);
            acc1 = fmaf(w1[jj], h1[jj], acc1);
        }
    }
    out[b * E_ + c] = sigm(acc0 + acc1 + b_fc[c]);
}

extern "C" void kernel_launch(void* const* d_in, const int* in_sizes, int n_in,
                              void* d_out, int out_size, void* d_ws, size_t ws_size,
                              hipStream_t stream)
{
    (void)in_sizes; (void)n_in; (void)out_size; (void)ws_size;
    const float* x      = (const float*)d_in[0];
    const float* memory = (const float*)d_in[1];
    const float* prev_r = (const float*)d_in[2];
    const float* prev_w = (const float*)d_in[3];
    const float* h_prev = (const float*)d_in[4];
    const float* c_prev = (const float*)d_in[5];
    const float* W_ih   = (const float*)d_in[6];
    const float* W_hh   = (const float*)d_in[7];
    const float* b_ih   = (const float*)d_in[8];
    const float* b_hh   = (const float*)d_in[9];
    const float* W_r    = (const float*)d_in[10];
    const float* b_r    = (const float*)d_in[11];
    const float* W_w    = (const float*)d_in[12];
    const float* b_w    = (const float*)d_in[13];
    const float* W_fc   = (const float*)d_in[14];
    const float* b_fc   = (const float*)d_in[15];

    float* ws = (float*)d_ws;
    float* gates = ws + OFF_GATES;
    float* h     = ws + OFF_H;
    float* kr    = ws + OFF_KR;
    float* kw    = ws + OFF_KW;
    float* e     = ws + OFF_E;
    float* a     = ws + OFF_A;
    float* scal  = ws + OFF_SCAL;
    float* dotr  = ws + OFF_DOTR;
    float* dotw  = ws + OFF_DOTW;
    float* mnorm = ws + OFF_MNORM;
    float* wrb   = ws + OFF_WR;
    float* wwb   = ws + OFF_WW;
    float* rdp   = ws + OFF_RDP;
    unsigned short* wsb = (unsigned short*)(ws + FLOAT_TOTAL);

    float* out    = (float*)d_out;
    float* newmem = out + B_ * E_;              // new_memory after out (f32)

    k_cvt2   <<<SHORT_TOTAL / 1024, 256, 0, stream>>>(x, h_prev, wsb);
    k_gates  <<<256,   256, 0, stream>>>(wsb, W_ih, W_hh, b_ih, b_hh, gates);
    k_ctrl   <<<256,   256, 0, stream>>>(gates, c_prev, W_r, b_r, W_w, b_w,
                                         h, kr, kw, e, a, scal);
    k_pass1  <<<4096,  256, 0, stream>>>(memory, kr, kw, dotr, dotw, mnorm);
    k_address<<<512,   256, 0, stream>>>(dotr, dotw, mnorm, prev_r, prev_w, scal, wrb, wwb);
    k_update <<<4096,  256, 0, stream>>>(memory, wrb, wwb, e, a, rdp, newmem);
    k_out    <<<512,   256, 0, stream>>>(h, rdp, W_fc, b_fc, out);
}